// Round 9
// baseline (124.101 us; speedup 1.0000x reference)
//
#include <hip/hip_runtime.h>
#include <hip/hip_bf16.h>
#include <stdint.h>

// KAN layer: out[b,o] = sum_{i,k} basis(tanh(x[b,i]))[k] * coeffs[o,i,k]
// GEMM M=8192, N=512, K=4096.
// R9 structure: cvt coeffs -> FRAGMENT-NATIVE Btf (ws, 4MB, L2-resident):
// each wave B-frag = one contiguous 1KB global_load_dwordx4 -> VGPR (no LDS
// for B, no R5 gather). basis(x)->A (ws). gemm: BM=128 BN=64 BK=64, 256 thr =
// 2 M-waves x 2 in-block K-groups, wave tile 64x64 (Wn=1: A frags read ONCE).
// A-only dbuf LDS 2grp x 2 x 16KB = 64KB -> grid 512 = 2 blocks/CU (two
// independent barrier domains). LDS/CU drops 9.2 -> 4.2 MB vs R8.

#define M_TOTAL 8192
#define N_DIM   512
#define K_DIM   4096
#define BM 128
#define BN 64
#define BK 64
#define NT_HALF 32          // K-tiles per K-group (2048/64)
#define ABUF 16384          // one A buffer (128 x 64 x bf16)
#define GRP_LDS 32768       // per-group arena: 2 A buffers

typedef __attribute__((ext_vector_type(8))) short short8;   // 8 x bf16
typedef __attribute__((ext_vector_type(4))) float f32x4;

typedef const __attribute__((address_space(1))) uint32_t ga_u32;
typedef __attribute__((address_space(3))) uint32_t ls_u32;

__device__ __forceinline__ void gload_lds16(const void* g, void* l) {
  // async global->LDS, 16B/lane; LDS dest = wave-uniform base + lane*16
  __builtin_amdgcn_global_load_lds((ga_u32*)(uintptr_t)g,
                                   (ls_u32*)(uint32_t)(uintptr_t)l, 16, 0, 0);
}

__device__ __forceinline__ uint32_t f2bf(float f) {
  uint32_t u = __builtin_bit_cast(uint32_t, f);
  return (u + 0x7FFFu + ((u >> 16) & 1u)) >> 16;
}

// cardinal cubic B-spline on uniform knots h=2/11; t=tanh(x) in (-1,1).
// 8 basis slots as 4xu32 packed bf16: w0..w3 land at slots c-3..c, rest 0.
__device__ __forceinline__ void basis_slots(float xv, uint32_t o[4]) {
  xv = fminf(15.f, fmaxf(-15.f, xv));
  float e  = __expf(2.0f * xv);
  float t  = (e - 1.0f) * __builtin_amdgcn_rcpf(e + 1.0f);
  float uf = (t + 1.0f) * 5.5f;            // /h
  int   c  = (int)uf;  c = c > 10 ? 10 : c;
  float u  = uf - (float)c;
  float u2 = u * u, u3 = u2 * u, om = 1.0f - u;
  float w0 = om * om * om * (1.0f / 6.0f);
  float w1 = (3.0f * u3 - 6.0f * u2 + 4.0f) * (1.0f / 6.0f);
  float w2 = (-3.0f * u3 + 3.0f * u2 + 3.0f * u + 1.0f) * (1.0f / 6.0f);
  float w3 = u3 * (1.0f / 6.0f);
  uint32_t p01 = f2bf(w0) | (f2bf(w1) << 16);
  uint32_t p23 = f2bf(w2) | (f2bf(w3) << 16);
  uint64_t W = (uint64_t)p01 | ((uint64_t)p23 << 32);
  int d = c - 3;                            // slot of w0, in [-3, 7]
  uint64_t lo = (d < 0) ? (W >> ((-d) * 16))
              : ((d < 4) ? (W << (d * 16)) : 0ull);
  uint64_t hi = (d <= 0) ? 0ull
              : ((d < 4) ? (W >> ((4 - d) * 16)) : (W << ((d - 4) * 16)));
  o[0] = (uint32_t)lo; o[1] = (uint32_t)(lo >> 32);
  o[2] = (uint32_t)hi; o[3] = (uint32_t)(hi >> 32);
}

// ---------------- basis kernel: one (b,i) per thread, 16B store --------------
__global__ __launch_bounds__(256) void basis_kernel(const float* __restrict__ x,
                                                    __hip_bfloat16* __restrict__ A,
                                                    int total) {
  int idx = blockIdx.x * 256 + threadIdx.x;
  if (idx >= total) return;
  uint32_t o[4];
  basis_slots(x[idx], o);
  reinterpret_cast<int4*>(A)[idx] = make_int4(o[0], o[1], o[2], o[3]);
}

// ------- coeff -> fragment-native Btf --------------------------------------
// frag g = (((nt*2+kgrp)*32+it)*2+kk)*4+ni ; element (g, lane) holds
// coef[o = nt*64+ni*16+(lane&15)][flat k = kgrp*2048+it*64+kk*32+(lane>>4)*8 + j]
// j=0..7 packed bf16 -> 16B at Btf + (g*64+lane)*16. GEMM B-frag load is then
// ONE contiguous 1KB wave load (lane*16 stride).
__global__ __launch_bounds__(256) void cvt_kernel(const float* __restrict__ c,
                                                  __hip_bfloat16* __restrict__ Btf,
                                                  int total) {
  int idx = blockIdx.x * 256 + threadIdx.x;   // = g*64 + lane
  if (idx >= total) return;
  int lane = idx & 63;
  int g    = idx >> 6;
  int ni   = g & 3;
  int kk   = (g >> 2) & 1;
  int it   = (g >> 3) & 31;
  int kgrp = (g >> 8) & 1;
  int nt   = g >> 9;                          // 0..7
  int n  = nt * 64 + ni * 16 + (lane & 15);
  int k0 = kgrp * 2048 + it * 64 + kk * 32 + (lane >> 4) * 8;
  const float4* src = reinterpret_cast<const float4*>(c + (size_t)n * K_DIM + k0);
  float4 a = src[0], b = src[1];
  union { unsigned short us[8]; int4 v; } pk;
  pk.us[0] = (unsigned short)f2bf(a.x); pk.us[1] = (unsigned short)f2bf(a.y);
  pk.us[2] = (unsigned short)f2bf(a.z); pk.us[3] = (unsigned short)f2bf(a.w);
  pk.us[4] = (unsigned short)f2bf(b.x); pk.us[5] = (unsigned short)f2bf(b.y);
  pk.us[6] = (unsigned short)f2bf(b.z); pk.us[7] = (unsigned short)f2bf(b.w);
  reinterpret_cast<int4*>(Btf)[idx] = pk.v;
}

// ---------------- GEMM: C[m,n] = sum_k A[m,k]*Btf[n,k] -----------------------
// 256 thr = 4 waves: kgrp = tid>>7, wv = (tid>>6)&1 (M-half). Wave tile 64x64.
__global__ __launch_bounds__(256, 2) void gemm_kernel(
    const __hip_bfloat16* __restrict__ A,    // [8192][4096]
    const __hip_bfloat16* __restrict__ Btf,  // fragment-native, 4MB
    float* __restrict__ C) {                 // [8192][512]
  __shared__ char lds[2 * GRP_LDS];          // 64 KB (A dbuf x 2 groups)

  const int tid  = threadIdx.x;
  const int lane = tid & 63;
  const int quad = lane >> 4;
  const int l16  = lane & 15;
  const int kgrp = tid >> 7;                 // 0..1: K-half
  const int wv   = (tid >> 6) & 1;           // M-half within group
  const int tg   = tid & 127;                // thread-in-group

  // XCD decode: per XCD 8 mt x 8 nt (Btf 4MB L2-resident, A stripes stream)
  const int b  = blockIdx.x;
  const int q  = b >> 3;                     // 0..63
  const int mt = (b & 7) * 8 + (q >> 3);     // 0..63
  const int nt = q & 7;                      // 0..7
  const int m0 = mt * BM;
  const int n0 = nt * BN;

  char* grp = lds + kgrp * GRP_LDS;

  // A staging: 1024 slots (16KB), 8 insts/thread over the group's 128 threads
  // slot s -> (row = s>>3, phys chunk p = s&7), src chunk cc = p ^ (row&7)
  uint32_t aGlob[8], sOff[8];
#pragma unroll
  for (int t = 0; t < 8; ++t) {
    int s = t * 128 + tg, row = s >> 3, p = s & 7, cc = p ^ (row & 7);
    sOff[t]  = (uint32_t)s * 16u;
    aGlob[t] = (uint32_t)(m0 + row) * K_DIM + (uint32_t)kgrp * 2048u
             + (uint32_t)cc * 8u;
  }

  // A fragment read offsets within a buffer
  uint32_t aOff[2][4];
#pragma unroll
  for (int kk = 0; kk < 2; ++kk) {
    int c = kk * 4 + quad;
#pragma unroll
    for (int mi = 0; mi < 4; ++mi) {
      int row = wv * 64 + mi * 16 + l16;
      aOff[kk][mi] = (uint32_t)(row * 8 + (c ^ (row & 7))) * 16u;
    }
  }

  // B frag base: frag (it,kk,ni) at bBase + it*8192 + kk*4096 + ni*1024
  const char* bBase = (const char*)Btf
      + (size_t)(nt * 2 + kgrp) * 32 * 8192 + (size_t)lane * 16;

  f32x4 acc[4][4];
#pragma unroll
  for (int mi = 0; mi < 4; ++mi)
#pragma unroll
    for (int ni = 0; ni < 4; ++ni)
      acc[mi][ni] = (f32x4){0.f, 0.f, 0.f, 0.f};

  short8 b0[2][4], b1[2][4];

#define STAGE_A(it, buf)                                                 \
  { _Pragma("unroll") for (int t = 0; t < 8; ++t)                        \
      gload_lds16(A + aGlob[t] + (uint32_t)(it) * 64u, (buf) + sOff[t]); }
#define LOAD_B(dst, it)                                                  \
  { _Pragma("unroll") for (int kk = 0; kk < 2; ++kk)                     \
      _Pragma("unroll") for (int ni = 0; ni < 4; ++ni)                   \
        dst[kk][ni] = *reinterpret_cast<const short8*>(                  \
            bBase + (it) * 8192 + kk * 4096 + ni * 1024); }
#define COMPUTE(buf, bR)                                                 \
  { _Pragma("unroll") for (int kk = 0; kk < 2; ++kk) {                   \
      short8 af[4];                                                      \
      _Pragma("unroll") for (int mi = 0; mi < 4; ++mi)                   \
        af[mi] = *reinterpret_cast<const short8*>((buf) + aOff[kk][mi]); \
      _Pragma("unroll") for (int mi = 0; mi < 4; ++mi)                   \
        _Pragma("unroll") for (int ni = 0; ni < 4; ++ni)                 \
          acc[mi][ni] = __builtin_amdgcn_mfma_f32_16x16x32_bf16(         \
              af[mi], bR[kk][ni], acc[mi][ni], 0, 0, 0); } }

  // prologue: tile 0 -> buf0 / b0
  STAGE_A(0, grp);
  LOAD_B(b0, 0);

  for (int it = 0; it < NT_HALF; it += 2) {
    __syncthreads();                        // A(it) resident in buf0
    if (it + 1 < NT_HALF) {
      STAGE_A(it + 1, grp + ABUF);
      LOAD_B(b1, it + 1);
    }
    COMPUTE(grp, b0);
    __syncthreads();                        // A(it+1) resident in buf1
    if (it + 2 < NT_HALF) {
      STAGE_A(it + 2, grp);
      LOAD_B(b0, it + 2);
    }
    COMPUTE(grp + ABUF, b1);
  }

  // split-K pair reduction: kgrp1 parks partials (32KB), kgrp0 sums + stores
  __syncthreads();
  if (kgrp == 1) {
#pragma unroll
    for (int mi = 0; mi < 4; ++mi)
#pragma unroll
      for (int ni = 0; ni < 4; ++ni) {
        int f = mi * 4 + ni;
        *reinterpret_cast<f32x4*>(lds + wv * 16384 + f * 1024 + lane * 16) =
            acc[mi][ni];
      }
  }
  __syncthreads();
  if (kgrp == 0) {
#pragma unroll
    for (int mi = 0; mi < 4; ++mi) {
#pragma unroll
      for (int ni = 0; ni < 4; ++ni) {
        int f = mi * 4 + ni;
        f32x4 other = *reinterpret_cast<f32x4*>(
            lds + wv * 16384 + f * 1024 + lane * 16);
        f32x4 s = acc[mi][ni] + other;
        int col = n0 + ni * 16 + l16;
#pragma unroll
        for (int r = 0; r < 4; ++r) {
          int row = m0 + wv * 64 + mi * 16 + quad * 4 + r;
          C[(size_t)row * N_DIM + col] = s[r];   // m89/m91 C/D layout
        }
      }
    }
  }
}

extern "C" void kernel_launch(void* const* d_in, const int* in_sizes, int n_in,
                              void* d_out, int out_size, void* d_ws, size_t ws_size,
                              hipStream_t stream) {
  const float* x    = (const float*)d_in[0];   // [8192,512]
  const float* coef = (const float*)d_in[1];   // [512,512,8]
  float* out = (float*)d_out;                  // [8192,512]

  __hip_bfloat16* Btf = (__hip_bfloat16*)d_ws;                      // 4 MB
  __hip_bfloat16* A   = (__hip_bfloat16*)((char*)d_ws + (size_t)4 * 1024 * 1024);
  // A = 64 MB; ws is ~268 MB (observed via harness poison fill), fits.

  const int total8 = N_DIM * K_DIM / 8;        // 262144 = 4096 frags x 64 lanes
  cvt_kernel<<<(total8 + 255) / 256, 256, 0, stream>>>(coef, Btf, total8);

  const int total = M_TOTAL * 512;             // (b,i) pairs
  basis_kernel<<<total / 256, 256, 0, stream>>>(x, A, total);

  gemm_kernel<<<(M_TOTAL / BM) * (N_DIM / BN), 256, 0, stream>>>(A, Btf, out);
}

// Round 10
// 119.960 us; speedup vs baseline: 1.0345x; 1.0345x over previous
//
#include <hip/hip_runtime.h>
#include <hip/hip_bf16.h>
#include <stdint.h>

// KAN layer: out[b,o] = sum_{i,k} basis(tanh(x[b,i]))[k] * coeffs[o,i,k]
// GEMM M=8192, N=512, K=4096.  cvt coeffs->Bt bf16 (ws) ; basis(x)->A (ws) ;
// gemm(A,Bt)->out.
// R6..R9 post-mortem: four distinct structures all land 44.5-48.5us with
// MfmaUtil 27-28% -> neither LDS BW nor barrier domains bind; it's the
// per-tile vmcnt(0)+barrier drain (the documented m97 plateau). R10: R6's
// exact shape (best, 44.5us) with BK=128 -> HALF the barrier/drain events
// at constant staging/frag/MFMA work. m132's BK=128 loss was occupancy
// (3->2 blocks/CU); moot here: grid=256 pins 1 block/CU regardless.
// LDS dbuf 2x64KB = 128KB <= 160KB.

#define M_TOTAL 8192
#define N_DIM   512
#define K_DIM   4096
#define BM 128
#define BN 128
#define BK 128
#define NTILES (K_DIM / BK)              // 32
#define ABYTES (BM * BK * 2)             // 32 KB
#define BUF_BYTES ((BM + BN) * BK * 2)   // 64 KB per LDS buffer

typedef __attribute__((ext_vector_type(8))) short short8;   // 8 x bf16
typedef __attribute__((ext_vector_type(4))) float f32x4;

typedef const __attribute__((address_space(1))) uint32_t ga_u32;
typedef __attribute__((address_space(3))) uint32_t ls_u32;

__device__ __forceinline__ void gload_lds16(const void* g, void* l) {
  // async global->LDS, 16B/lane; LDS dest = wave-uniform base + lane*16
  __builtin_amdgcn_global_load_lds((ga_u32*)(uintptr_t)g,
                                   (ls_u32*)(uint32_t)(uintptr_t)l, 16, 0, 0);
}

__device__ __forceinline__ uint32_t f2bf(float f) {
  uint32_t u = __builtin_bit_cast(uint32_t, f);
  return (u + 0x7FFFu + ((u >> 16) & 1u)) >> 16;
}

// cardinal cubic B-spline on uniform knots h=2/11; t=tanh(x) in (-1,1).
// 8 basis slots as 4xu32 packed bf16: w0..w3 land at slots c-3..c, rest 0.
__device__ __forceinline__ void basis_slots(float xv, uint32_t o[4]) {
  xv = fminf(15.f, fmaxf(-15.f, xv));
  float e  = __expf(2.0f * xv);
  float t  = (e - 1.0f) * __builtin_amdgcn_rcpf(e + 1.0f);
  float uf = (t + 1.0f) * 5.5f;            // /h
  int   c  = (int)uf;  c = c > 10 ? 10 : c;
  float u  = uf - (float)c;
  float u2 = u * u, u3 = u2 * u, om = 1.0f - u;
  float w0 = om * om * om * (1.0f / 6.0f);
  float w1 = (3.0f * u3 - 6.0f * u2 + 4.0f) * (1.0f / 6.0f);
  float w2 = (-3.0f * u3 + 3.0f * u2 + 3.0f * u + 1.0f) * (1.0f / 6.0f);
  float w3 = u3 * (1.0f / 6.0f);
  uint32_t p01 = f2bf(w0) | (f2bf(w1) << 16);
  uint32_t p23 = f2bf(w2) | (f2bf(w3) << 16);
  uint64_t W = (uint64_t)p01 | ((uint64_t)p23 << 32);
  int d = c - 3;                            // slot of w0, in [-3, 7]
  uint64_t lo = (d < 0) ? (W >> ((-d) * 16))
              : ((d < 4) ? (W << (d * 16)) : 0ull);
  uint64_t hi = (d <= 0) ? 0ull
              : ((d < 4) ? (W >> ((4 - d) * 16)) : (W << ((d - 4) * 16)));
  o[0] = (uint32_t)lo; o[1] = (uint32_t)(lo >> 32);
  o[2] = (uint32_t)hi; o[3] = (uint32_t)(hi >> 32);
}

// ---------------- basis kernel: one (b,i) per thread, 16B store --------------
__global__ __launch_bounds__(256) void basis_kernel(const float* __restrict__ x,
                                                    __hip_bfloat16* __restrict__ A,
                                                    int total) {
  int idx = blockIdx.x * 256 + threadIdx.x;
  if (idx >= total) return;
  uint32_t o[4];
  basis_slots(x[idx], o);
  reinterpret_cast<int4*>(A)[idx] = make_int4(o[0], o[1], o[2], o[3]);
}

// ---------------- coeff cast: [512][512][8] fp32 -> bf16 (== B^T[512][4096]) --
__global__ __launch_bounds__(256) void cvt_kernel(const float* __restrict__ c,
                                                  __hip_bfloat16* __restrict__ Bt,
                                                  int total8) {
  int idx = blockIdx.x * 256 + threadIdx.x;
  if (idx >= total8) return;
  const float4* cp = reinterpret_cast<const float4*>(c) + (size_t)idx * 2;
  float4 a = cp[0], b = cp[1];
  union { unsigned short us[8]; int4 v; } pk;
  pk.us[0] = (unsigned short)f2bf(a.x); pk.us[1] = (unsigned short)f2bf(a.y);
  pk.us[2] = (unsigned short)f2bf(a.z); pk.us[3] = (unsigned short)f2bf(a.w);
  pk.us[4] = (unsigned short)f2bf(b.x); pk.us[5] = (unsigned short)f2bf(b.y);
  pk.us[6] = (unsigned short)f2bf(b.z); pk.us[7] = (unsigned short)f2bf(b.w);
  reinterpret_cast<int4*>(Bt)[idx] = pk.v;
}

// ---------------- GEMM: C[m,n] = sum_k A[m,k]*Bt[n,k] ------------------------
// 512 thr = 8 waves, wave grid 2(M) x 4(N), wave tile 64x32 (4x2 frags).
// BK=128: rows have 16 chunks of 16B; XOR swizzle cc = p ^ (row & 15).
__global__ __launch_bounds__(512) void gemm_kernel(
    const __hip_bfloat16* __restrict__ A,   // [8192][4096]
    const __hip_bfloat16* __restrict__ Bt,  // [512][4096]
    float* __restrict__ C) {                // [8192][512]
  __shared__ char lds[2 * BUF_BYTES];       // 128 KB

  const int tid   = threadIdx.x;
  const int wid   = tid >> 6;               // 0..7
  const int lane  = tid & 63;
  const int quad  = lane >> 4;
  const int l16   = lane & 15;
  const int waveM = wid >> 2;               // 0..1
  const int waveN = wid & 3;                // 0..3

  // XCD decode: each XCD owns 8 M-stripes x all 4 N-tiles; Bt (4MB) stays
  // L2-resident per XCD, A-stripes stream through once.
  const int b  = blockIdx.x;
  const int q  = b >> 3;                    // 0..31
  const int mt = (b & 7) * 8 + (q >> 2);    // 0..63
  const int nt = q & 3;                     // 0..3
  const int m0 = mt * BM;
  const int n0 = nt * BN;

  // staging: slot s -> (row = s>>4, phys chunk p = s&15); src cc = p^(row&15)
  // A: 2048 slots (32KB) at buf+0; B: 2048 slots at buf+32KB. 4 insts each.
  uint32_t aGlob[4], sAOff[4], bGlob[4], sBOff[4];
#pragma unroll
  for (int t = 0; t < 4; ++t) {
    int s = t * 512 + tid, row = s >> 4, p = s & 15, cc = p ^ (row & 15);
    sAOff[t] = (uint32_t)s * 16u;
    sBOff[t] = (uint32_t)ABYTES + (uint32_t)s * 16u;
    aGlob[t] = (uint32_t)(m0 + row) * K_DIM + (uint32_t)cc * 8u;
    bGlob[t] = (uint32_t)(n0 + row) * K_DIM + (uint32_t)cc * 8u;
  }

  // fragment read offsets within a buffer (A at +0, B at +32KB)
  uint32_t aOff[4][4], bOff[4][2];
#pragma unroll
  for (int kk = 0; kk < 4; ++kk) {
    int c = kk * 4 + quad;                  // chunk 0..15
#pragma unroll
    for (int mi = 0; mi < 4; ++mi) {
      int row = waveM * 64 + mi * 16 + l16;
      aOff[kk][mi] = (uint32_t)(row * 16 + (c ^ (row & 15))) * 16u;
    }
#pragma unroll
    for (int ni = 0; ni < 2; ++ni) {
      int row = waveN * 32 + ni * 16 + l16;
      bOff[kk][ni] = (uint32_t)ABYTES
                   + (uint32_t)(row * 16 + (c ^ (row & 15))) * 16u;
    }
  }

  char* ldsc = (char*)lds;

  f32x4 acc[4][2];
#pragma unroll
  for (int mi = 0; mi < 4; ++mi)
#pragma unroll
    for (int ni = 0; ni < 2; ++ni)
      acc[mi][ni] = (f32x4){0.f, 0.f, 0.f, 0.f};

  // prologue: stage tile 0 into buffer 0
#pragma unroll
  for (int t = 0; t < 4; ++t) {
    gload_lds16(A + aGlob[t], ldsc + sAOff[t]);
    gload_lds16(Bt + bGlob[t], ldsc + sBOff[t]);
  }

  for (int it = 0; it < NTILES; ++it) {
    const int cur = it & 1;
    char* bufc = ldsc + cur * BUF_BYTES;
    __syncthreads();                        // staging for tile it drained
    if (it + 1 < NTILES) {                  // stage it+1 under compute of it
      char* bufn = ldsc + (1 - cur) * BUF_BYTES;
      uint32_t kt = (uint32_t)(it + 1) * BK;
#pragma unroll
      for (int t = 0; t < 4; ++t) {
        gload_lds16(A + aGlob[t] + kt, bufn + sAOff[t]);
        gload_lds16(Bt + bGlob[t] + kt, bufn + sBOff[t]);
      }
    }
#pragma unroll
    for (int kk = 0; kk < 4; ++kk) {
      short8 af[4], bf[2];
#pragma unroll
      for (int mi = 0; mi < 4; ++mi)
        af[mi] = *reinterpret_cast<const short8*>(bufc + aOff[kk][mi]);
#pragma unroll
      for (int ni = 0; ni < 2; ++ni)
        bf[ni] = *reinterpret_cast<const short8*>(bufc + bOff[kk][ni]);
#pragma unroll
      for (int mi = 0; mi < 4; ++mi)
#pragma unroll
        for (int ni = 0; ni < 2; ++ni)
          acc[mi][ni] = __builtin_amdgcn_mfma_f32_16x16x32_bf16(
              af[mi], bf[ni], acc[mi][ni], 0, 0, 0);
    }
  }

  // epilogue: D row = quad*4 + r, col = l16 (m89/m91-verified C/D layout)
#pragma unroll
  for (int mi = 0; mi < 4; ++mi) {
#pragma unroll
    for (int ni = 0; ni < 2; ++ni) {
      int col = n0 + waveN * 32 + ni * 16 + l16;
#pragma unroll
      for (int r = 0; r < 4; ++r) {
        int row = m0 + waveM * 64 + mi * 16 + quad * 4 + r;
        C[(size_t)row * N_DIM + col] = acc[mi][ni][r];
      }
    }
  }
}

extern "C" void kernel_launch(void* const* d_in, const int* in_sizes, int n_in,
                              void* d_out, int out_size, void* d_ws, size_t ws_size,
                              hipStream_t stream) {
  const float* x    = (const float*)d_in[0];   // [8192,512]
  const float* coef = (const float*)d_in[1];   // [512,512,8]
  float* out = (float*)d_out;                  // [8192,512]

  __hip_bfloat16* Bt = (__hip_bfloat16*)d_ws;                       // 4 MB
  __hip_bfloat16* A  = (__hip_bfloat16*)((char*)d_ws + (size_t)4 * 1024 * 1024);
  // A = 64 MB; ws is ~268 MB (observed via harness poison fill), fits.

  const int total8 = N_DIM * K_DIM / 8;        // 262144
  cvt_kernel<<<(total8 + 255) / 256, 256, 0, stream>>>(coef, Bt, total8);

  const int total = M_TOTAL * 512;             // (b,i) pairs
  basis_kernel<<<total / 256, 256, 0, stream>>>(x, A, total);

  gemm_kernel<<<(M_TOTAL / BM) * (N_DIM / BN), 512, 0, stream>>>(A, Bt, out);
}